// Round 5
// baseline (310.110 us; speedup 1.0000x reference)
//
#include <hip/hip_runtime.h>
#include <hip/hip_bf16.h>
#include <cstddef>
#include <cstdint>

typedef __attribute__((ext_vector_type(4))) __bf16 bf16x4;
typedef __attribute__((ext_vector_type(8))) __bf16 bf16x8;
typedef __attribute__((ext_vector_type(4))) float f32x4;

#define L_SEQ 2048
#define KD 768           // inner dim (nhid)
#define N_HEAD 12
#define NB 4
#define NX 8192          // B*L
#define NALL 49152       // B*L*(1+5)
#define NT_STEPS 24      // KD / 32
#define KVLD 1536        // merged K|V output row length

// 16B async global->LDS. LDS dest is wave-uniform base + lane*16.
__device__ __forceinline__ void gload16(const __bf16* g, __bf16* l) {
    __builtin_amdgcn_global_load_lds(
        (const __attribute__((address_space(1))) void*)g,
        (__attribute__((address_space(3))) void*)l, 16, 0, 0);
}

// ---------------- weight fp32 -> bf16 (4 matrices of 768x768) ----------------
__global__ __launch_bounds__(256) void wconv_kernel(
    const float* __restrict__ W0, const float* __restrict__ W1,
    const float* __restrict__ W2, const float* __restrict__ W3,
    __bf16* __restrict__ O0, __bf16* __restrict__ O1,
    __bf16* __restrict__ O2, __bf16* __restrict__ O3)
{
    const float* src; __bf16* dst;
    switch (blockIdx.y) {
        case 0: src = W0; dst = O0; break;
        case 1: src = W1; dst = O1; break;
        case 2: src = W2; dst = O2; break;
        default: src = W3; dst = O3; break;
    }
    const int i = (blockIdx.x * 256 + threadIdx.x) * 4;
    const float4 v = *(const float4*)(src + i);
    bf16x4 t;
    t[0] = (__bf16)v.x; t[1] = (__bf16)v.y; t[2] = (__bf16)v.z; t[3] = (__bf16)v.w;
    *(bf16x4*)(dst + i) = t;
}

// ------------- convert+transpose all 6 a'-chunks into XT[n'(49152)][768] -------------
__global__ __launch_bounds__(256) void xconv_kernel(
    const float* __restrict__ x, const float* __restrict__ ax,
    __bf16* __restrict__ XT)
{
    __shared__ __bf16 S[64][72];
    const int t = threadIdx.x;
    const int ap = blockIdx.x >> 7;
    const int inner = blockIdx.x & 127;
    const int bb = inner >> 5;
    const int l0 = (inner & 31) * 64;
    const int d0 = blockIdx.y * 64;
    const int r = t >> 4;
    const int c4 = (t & 15) * 4;
    #pragma unroll
    for (int p = 0; p < 4; ++p) {
        const int d = d0 + r + p * 16;
        const float* src = (ap == 0)
            ? x + ((size_t)(bb * KD + d)) * L_SEQ
            : ax + (((size_t)(bb * KD + d)) * 5 + (ap - 1)) * L_SEQ;
        const float4 v = *(const float4*)(src + l0 + c4);
        S[c4 + 0][r + p * 16] = (__bf16)v.x;
        S[c4 + 1][r + p * 16] = (__bf16)v.y;
        S[c4 + 2][r + p * 16] = (__bf16)v.z;
        S[c4 + 3][r + p * 16] = (__bf16)v.w;
    }
    __syncthreads();
    #pragma unroll
    for (int p = 0; p < 4; ++p) {
        const int lr = r + p * 16;
        const bf16x4 v = *(const bf16x4*)&S[lr][c4];
        *(bf16x4*)(XT + ((size_t)ap * NX + bb * L_SEQ + l0 + lr) * KD + d0 + c4) = v;
    }
}

// ---------------- 256x256 BK=32 quad-buffered counted-vmcnt GEMM ----------------
// Out = A(row-major [M][768]) * Bt(row-major [N][768])^T + bias.
// 512 thr = 8 waves (2M x 4N); per-wave 128x64 out = acc[8][4] f32x4.
// LDS: 4 bufs x 32 KB. Swizzle (both sides, involution): 16B-slot ^= (row>>1)&3
// -> each 8-lane b128 group covers all 32 banks exactly once.
// Schedule per K-step: vmcnt(8) -> s_barrier -> stage(t+3) -> ds_read(t) -> 32 MFMA.
template <int MODE>   // 0: bf16 OutT[n'][ldo] (LDS-transposed); 1: fp32 out[(b*768+m)*2048+l]
__device__ __forceinline__ void gemm256_body(
    const __bf16* __restrict__ A, const __bf16* __restrict__ Bt,
    const float* __restrict__ bias, void* __restrict__ Out, int ldo,
    int m0, int n0, __bf16* SL)
{
    const int tid = threadIdx.x;
    const int lane = tid & 63, wv = tid >> 6;
    const int wm = wv >> 2, wn = wv & 3;
    const int lr = lane & 15;
    const int kslc = lane >> 4;                    // 0..3 (k-slot of MFMA frag)
    const int slotp = kslc ^ ((lr >> 1) & 3);      // swizzled slot for ds_read
    const int srow = lane >> 2;                    // staging: row within 16-row chunk
    const int skoff = ((lane & 3) ^ ((lane >> 3) & 3)) * 8;  // inverse-swizzled src k offset

    f32x4 acc[8][4];
    #pragma unroll
    for (int i = 0; i < 8; ++i)
        #pragma unroll
        for (int j = 0; j < 4; ++j)
            acc[i][j] = (f32x4){0.f, 0.f, 0.f, 0.f};

    auto STAGE = [&](int t) {
        const int bufo = (t & 3) * 16384;
        const int k0 = t * 32;
        #pragma unroll
        for (int i = 0; i < 2; ++i) {
            const int c = wv + i * 8;               // wave-uniform chunk id
            const int row = c * 16 + srow;
            gload16(A  + (size_t)(m0 + row) * KD + k0 + skoff, SL + bufo + c * 512);
            gload16(Bt + (size_t)(n0 + row) * KD + k0 + skoff, SL + bufo + 8192 + c * 512);
        }
    };

    STAGE(0); STAGE(1); STAGE(2);

    #pragma unroll
    for (int t = 0; t < NT_STEPS; ++t) {
        if (t < NT_STEPS - 2)      asm volatile("s_waitcnt vmcnt(8)" ::: "memory");
        else if (t == NT_STEPS - 2) asm volatile("s_waitcnt vmcnt(4)" ::: "memory");
        else                        asm volatile("s_waitcnt vmcnt(0)" ::: "memory");
        __builtin_amdgcn_s_barrier();
        asm volatile("" ::: "memory");       // fence: keep ds_reads below the barrier
        if (t < NT_STEPS - 3) STAGE(t + 3);
        const int bufo = (t & 3) * 16384;
        const __bf16* pA = SL + bufo + (wm * 128 + lr) * 32 + slotp * 8;
        const __bf16* pB = SL + bufo + 8192 + (wn * 64 + lr) * 32 + slotp * 8;
        bf16x8 af[8], bq_[4];
        #pragma unroll
        for (int i = 0; i < 8; ++i) af[i] = *(const bf16x8*)(pA + i * 512);
        #pragma unroll
        for (int j = 0; j < 4; ++j) bq_[j] = *(const bf16x8*)(pB + j * 512);
        __builtin_amdgcn_s_setprio(1);
        #pragma unroll
        for (int i = 0; i < 8; ++i)
            #pragma unroll
            for (int j = 0; j < 4; ++j)
                acc[i][j] = __builtin_amdgcn_mfma_f32_16x16x32_bf16(af[i], bq_[j], acc[i][j], 0, 0, 0);
        __builtin_amdgcn_s_setprio(0);
    }

    // bias (C/D: col=lane&15, row=(lane>>4)*4+reg); bias ptr is pre-offset for m0>=768
    const int row0 = kslc * 4;
    #pragma unroll
    for (int i = 0; i < 8; ++i)
        #pragma unroll
        for (int r = 0; r < 4; ++r) {
            const float bb = bias[m0 + wm * 128 + i * 16 + row0 + r];
            #pragma unroll
            for (int j = 0; j < 4; ++j) acc[i][j][r] += bb;
        }

    if (MODE == 0) {
        __bf16* T = SL + wv * 2176;          // 16 x 136 per wave
        #pragma unroll
        for (int j = 0; j < 4; ++j) {
            __syncthreads();
            #pragma unroll
            for (int i = 0; i < 8; ++i)
                #pragma unroll
                for (int r = 0; r < 4; ++r)
                    T[lr * 136 + i * 16 + row0 + r] = (__bf16)acc[i][j][r];
            __syncthreads();
            const int rr = lane >> 2, seg = lane & 3;
            __bf16* dst = (__bf16*)Out + (size_t)(n0 + wn * 64 + j * 16 + rr) * ldo
                          + m0 + wm * 128 + seg * 32;
            const __bf16* src = T + rr * 136 + seg * 32;
            #pragma unroll
            for (int s = 0; s < 4; ++s)
                *(bf16x8*)(dst + s * 8) = *(const bf16x8*)(src + s * 8);
        }
    } else {
        const int b_ = n0 >> 11;
        const int l0 = (n0 & 2047) + wn * 64;
        float* o = (float*)Out;
        #pragma unroll
        for (int i = 0; i < 8; ++i)
            #pragma unroll
            for (int r = 0; r < 4; ++r) {
                const int mg = m0 + wm * 128 + i * 16 + row0 + r;
                #pragma unroll
                for (int j = 0; j < 4; ++j)
                    o[((size_t)(b_ * KD + mg)) * L_SEQ + l0 + j * 16 + lr] = acc[i][j][r];
            }
    }
}

// merged K|V projection: A = [Wk;Wv] (1536x768, contiguous), Out = KVt[49152][1536]
__global__ __launch_bounds__(512, 2) void gemm256_kv(
    const __bf16* __restrict__ Wkv, const float* __restrict__ bk, const float* __restrict__ bv,
    const __bf16* __restrict__ XT, __bf16* __restrict__ KVt)
{
    extern __shared__ __bf16 SL[];
    const int m0 = blockIdx.x * 256;                    // 0..1280 (never crosses 768)
    const int n0 = blockIdx.y * 256;
    const float* biasp = (m0 < 768) ? bk : (bv - 768);  // biasp[m] valid for this block's m
    gemm256_body<0>(Wkv, XT, biasp, KVt, KVLD, m0, n0, SL);
}

template <int MODE>
__global__ __launch_bounds__(512, 2) void gemm256_one(
    const __bf16* __restrict__ W, const float* __restrict__ bias,
    const __bf16* __restrict__ Bt, void* __restrict__ Out)
{
    extern __shared__ __bf16 SL[];
    gemm256_body<MODE>(W, Bt, bias, Out, KD, blockIdx.y * 256, blockIdx.x * 256, SL);
}

// ---------------- attention (all transposed, 16B loads) ----------------
// Qt: [8192][768]; KVt: [49152][1536] (K at +0, V at +768); attT: [8192][768]
__global__ __launch_bounds__(256) void attn_kernel(
    const __bf16* __restrict__ Qt, const __bf16* __restrict__ KVt,
    __bf16* __restrict__ attT)
{
    const int bid = blockIdx.x;
    const int lt = bid & 63;
    const int h = bid >> 6;
    const int tid = threadIdx.x;
    const int wave = tid >> 6, lane = tid & 63;
    const int half = lane >> 5, ln = lane & 31;
    const int n = lt * 128 + wave * 32 + ln;
    const int l = n & (L_SEQ - 1);
    const int c0 = h * 64 + half * 32;

    float q[32];
    {
        const __bf16* qp = Qt + (size_t)n * KD + c0;
        #pragma unroll
        for (int s = 0; s < 4; ++s) {
            const bf16x8 v = *(const bf16x8*)(qp + s * 8);
            #pragma unroll
            for (int j = 0; j < 8; ++j) q[s * 8 + j] = (float)v[j];
        }
    }

    float sc[10];
    #pragma unroll
    for (int w = 0; w < 5; ++w) {
        const int lw = l + w - 2;
        float acc = 0.f;
        if ((unsigned)lw < L_SEQ) {
            const __bf16* kp = KVt + (size_t)(n + w - 2) * KVLD + c0;
            #pragma unroll
            for (int s = 0; s < 4; ++s) {
                const bf16x8 v = *(const bf16x8*)(kp + s * 8);
                #pragma unroll
                for (int j = 0; j < 8; ++j) acc += q[s * 8 + j] * (float)v[j];
            }
        }
        sc[w] = acc;
    }
    #pragma unroll
    for (int a = 0; a < 5; ++a) {
        const __bf16* kp = KVt + ((size_t)(a + 1) * NX + n) * KVLD + c0;
        float acc = 0.f;
        #pragma unroll
        for (int s = 0; s < 4; ++s) {
            const bf16x8 v = *(const bf16x8*)(kp + s * 8);
            #pragma unroll
            for (int j = 0; j < 8; ++j) acc += q[s * 8 + j] * (float)v[j];
        }
        sc[5 + a] = acc;
    }

    #pragma unroll
    for (int i = 0; i < 10; ++i) {
        sc[i] += __shfl_xor(sc[i], 32);
        sc[i] *= 0.125f;
    }

    float mx = sc[0];
    #pragma unroll
    for (int i = 1; i < 10; ++i) mx = fmaxf(mx, sc[i]);
    float e[10], sum = 0.f;
    #pragma unroll
    for (int i = 0; i < 10; ++i) { e[i] = __expf(sc[i] - mx); sum += e[i]; }
    const float inv = 1.f / sum;

    float o[32];
    #pragma unroll
    for (int i = 0; i < 32; ++i) o[i] = 0.f;

    #pragma unroll
    for (int w = 0; w < 5; ++w) {
        const int lw = l + w - 2;
        if ((unsigned)lw < L_SEQ) {
            const __bf16* vp = KVt + (size_t)(n + w - 2) * KVLD + 768 + c0;
            #pragma unroll
            for (int s = 0; s < 4; ++s) {
                const bf16x8 v = *(const bf16x8*)(vp + s * 8);
                #pragma unroll
                for (int j = 0; j < 8; ++j) o[s * 8 + j] += e[w] * (float)v[j];
            }
        }
    }
    #pragma unroll
    for (int a = 0; a < 5; ++a) {
        const __bf16* vp = KVt + ((size_t)(a + 1) * NX + n) * KVLD + 768 + c0;
        #pragma unroll
        for (int s = 0; s < 4; ++s) {
            const bf16x8 v = *(const bf16x8*)(vp + s * 8);
            #pragma unroll
            for (int j = 0; j < 8; ++j) o[s * 8 + j] += e[5 + a] * (float)v[j];
        }
    }

    __bf16* dst = attT + (size_t)n * KD + c0;
    #pragma unroll
    for (int s = 0; s < 4; ++s) {
        bf16x8 t;
        #pragma unroll
        for (int j = 0; j < 8; ++j) t[j] = (__bf16)(o[s * 8 + j] * inv);
        *(bf16x8*)(dst + s * 8) = t;
    }
}

extern "C" void kernel_launch(void* const* d_in, const int* in_sizes, int n_in,
                              void* d_out, int out_size, void* d_ws, size_t ws_size,
                              hipStream_t stream)
{
    const float* x  = (const float*)d_in[0];
    const float* ax = (const float*)d_in[1];
    const float* Wq = (const float*)d_in[2];
    const float* bq = (const float*)d_in[3];
    const float* Wk = (const float*)d_in[4];
    const float* bk = (const float*)d_in[5];
    const float* Wv = (const float*)d_in[6];
    const float* bv = (const float*)d_in[7];
    const float* Wo = (const float*)d_in[8];
    const float* bo = (const float*)d_in[9];
    float* out = (float*)d_out;

    __bf16* p = (__bf16*)d_ws;
    __bf16* Wq_bf = p; p += 589824;
    __bf16* Wkv_bf = p;                       // = [Wk_bf; Wv_bf] contiguous
    __bf16* Wk_bf = p; p += 589824;
    __bf16* Wv_bf = p; p += 589824;
    __bf16* Wo_bf = p; p += 589824;
    __bf16* Qt    = p; p += (size_t)KD * NX;      // 6.29M
    __bf16* KVt   = p; p += (size_t)KVLD * NALL;  // 75.5M
    __bf16* XT    = p; p += (size_t)KD * NALL;    // 37.7M
    __bf16* attT  = p;
    // total ws use: ~256 MB

    const size_t lds = 131072;

    wconv_kernel<<<dim3(576, 4), dim3(256), 0, stream>>>(Wq, Wk, Wv, Wo, Wq_bf, Wk_bf, Wv_bf, Wo_bf);
    xconv_kernel<<<dim3(768, 12), dim3(256), 0, stream>>>(x, ax, XT);

    gemm256_kv<<<dim3(6, 192), dim3(512), lds, stream>>>(Wkv_bf, bk, bv, XT, KVt);
    gemm256_one<0><<<dim3(32, 3), dim3(512), lds, stream>>>(Wq_bf, bq, XT, Qt);

    attn_kernel<<<dim3(64 * N_HEAD), dim3(256), 0, stream>>>(Qt, KVt, attT);

    gemm256_one<1><<<dim3(32, 3), dim3(512), lds, stream>>>(Wo_bf, bo, attT, out);
}

// Round 6
// 308.710 us; speedup vs baseline: 1.0045x; 1.0045x over previous
//
#include <hip/hip_runtime.h>
#include <hip/hip_bf16.h>
#include <cstddef>
#include <cstdint>

typedef __attribute__((ext_vector_type(4))) __bf16 bf16x4;
typedef __attribute__((ext_vector_type(8))) __bf16 bf16x8;
typedef __attribute__((ext_vector_type(4))) float f32x4;

#define L_SEQ 2048
#define KD 768
#define N_HEAD 12
#define NB 4
#define NX 8192          // B*L
#define NALL 49152       // B*L*(1+5)
#define KVLD 1536        // merged K|V output row length

#define FENCE asm volatile("" ::: "memory")
#define BARRIER do { FENCE; __builtin_amdgcn_s_barrier(); FENCE; } while (0)

__device__ __forceinline__ void gload16(const __bf16* g, __bf16* l) {
    __builtin_amdgcn_global_load_lds(
        (const __attribute__((address_space(1))) void*)g,
        (__attribute__((address_space(3))) void*)l, 16, 0, 0);
}

// ---------------- weight fp32 -> bf16 ----------------
__global__ __launch_bounds__(256) void wconv_kernel(
    const float* __restrict__ W0, const float* __restrict__ W1,
    const float* __restrict__ W2, const float* __restrict__ W3,
    __bf16* __restrict__ O0, __bf16* __restrict__ O1,
    __bf16* __restrict__ O2, __bf16* __restrict__ O3)
{
    const float* src; __bf16* dst;
    switch (blockIdx.y) {
        case 0: src = W0; dst = O0; break;
        case 1: src = W1; dst = O1; break;
        case 2: src = W2; dst = O2; break;
        default: src = W3; dst = O3; break;
    }
    const int i = (blockIdx.x * 256 + threadIdx.x) * 4;
    const float4 v = *(const float4*)(src + i);
    bf16x4 t;
    t[0] = (__bf16)v.x; t[1] = (__bf16)v.y; t[2] = (__bf16)v.z; t[3] = (__bf16)v.w;
    *(bf16x4*)(dst + i) = t;
}

// ------------- convert+transpose into XT[n'(49152)][768] -------------
__global__ __launch_bounds__(256) void xconv_kernel(
    const float* __restrict__ x, const float* __restrict__ ax,
    __bf16* __restrict__ XT)
{
    __shared__ __bf16 S[64][72];
    const int t = threadIdx.x;
    const int ap = blockIdx.x >> 7;
    const int inner = blockIdx.x & 127;
    const int bb = inner >> 5;
    const int l0 = (inner & 31) * 64;
    const int d0 = blockIdx.y * 64;
    const int r = t >> 4;
    const int c4 = (t & 15) * 4;
    #pragma unroll
    for (int p = 0; p < 4; ++p) {
        const int d = d0 + r + p * 16;
        const float* src = (ap == 0)
            ? x + ((size_t)(bb * KD + d)) * L_SEQ
            : ax + (((size_t)(bb * KD + d)) * 5 + (ap - 1)) * L_SEQ;
        const float4 v = *(const float4*)(src + l0 + c4);
        S[c4 + 0][r + p * 16] = (__bf16)v.x;
        S[c4 + 1][r + p * 16] = (__bf16)v.y;
        S[c4 + 2][r + p * 16] = (__bf16)v.z;
        S[c4 + 3][r + p * 16] = (__bf16)v.w;
    }
    __syncthreads();
    #pragma unroll
    for (int p = 0; p < 4; ++p) {
        const int lr = r + p * 16;
        const bf16x4 v = *(const bf16x4*)&S[lr][c4];
        *(bf16x4*)(XT + ((size_t)ap * NX + bb * L_SEQ + l0 + lr) * KD + d0 + c4) = v;
    }
}

// ---------------- 256x256 phase-split GEMM (2 phases / BK=32 step) ----------------
// Out = A[M][768] * Bt[N][768]^T + bias. 8 waves (2M x 4N), per-wave 128x64 (acc[8][4]).
// LDS: 3-deep ring of (A-plane 16KB + B-plane 16KB) = 96 KiB.
// Per step t: phase A {ds_read af[0..3]+bq[0..3]; stage A-plane(t+2); BAR; lgkm0; 16 MFMA; BAR}
//             phase B {ds_read af[4..7];           stage B-plane(t+2); vmcnt(4|0); BAR; lgkm0; 16 MFMA; BAR}
// vmcnt(4) before the barrier => every wave's stage-writes for step t+1 landed before
// any wave reads them at t+1 (steady outstanding = 8: 4 for t+1 + 4 for t+2).
// Swizzle pair (verified R4): stage fetches gk-slot (lane&3)^((lane>>3)&3); read slot kslc^((lr>>1)&3).
template <int MODE, int NM>   // MODE 0: bf16 OutT[n'][ldo]; MODE 1: fp32 out[(b*768+m)*2048+l]
__global__ __launch_bounds__(512, 2) void gemm256_kernel(
    const __bf16* __restrict__ A, const __bf16* __restrict__ Bt,
    const float* __restrict__ bias_lo, const float* __restrict__ bias_hi,
    void* __restrict__ Out, int ldo)
{
    extern __shared__ __bf16 SL[];
    // XCD-grouped swizzle: same-n-panel m-blocks land consecutively on one XCD
    const int nwg8 = gridDim.x >> 3;
    const int gidx = (blockIdx.x & 7) * nwg8 + (blockIdx.x >> 3);
    const int m0 = (gidx % NM) * 256;
    const int n0 = (gidx / NM) * 256;

    const int tid = threadIdx.x;
    const int lane = tid & 63, wv = tid >> 6;
    const int wm = wv >> 2, wn = wv & 3;
    const int lr = lane & 15;
    const int kslc = lane >> 4;
    const int slotp = kslc ^ ((lr >> 1) & 3);
    const int srow = lane >> 2;
    const int skoff = ((lane & 3) ^ ((lane >> 3) & 3)) * 8;

    f32x4 acc[8][4];
    #pragma unroll
    for (int i = 0; i < 8; ++i)
        #pragma unroll
        for (int j = 0; j < 4; ++j)
            acc[i][j] = (f32x4){0.f, 0.f, 0.f, 0.f};

    const size_t gbA = (size_t)m0 * KD + skoff;
    const size_t gbB = (size_t)n0 * KD + skoff;

    auto stageA = [&](int t) {
        __bf16* dst = SL + (t % 3) * 16384;
        #pragma unroll
        for (int i2 = 0; i2 < 2; ++i2) {
            const int c = wv + i2 * 8;
            gload16(A + gbA + (size_t)(c * 16 + srow) * KD + t * 32, dst + c * 512);
        }
    };
    auto stageB = [&](int t) {
        __bf16* dst = SL + (t % 3) * 16384 + 8192;
        #pragma unroll
        for (int i2 = 0; i2 < 2; ++i2) {
            const int c = wv + i2 * 8;
            gload16(Bt + gbB + (size_t)(c * 16 + srow) * KD + t * 32, dst + c * 512);
        }
    };

    // prologue: steps 0 and 1 in flight
    stageA(0); stageB(0); stageA(1); stageB(1);
    asm volatile("s_waitcnt vmcnt(4)" ::: "memory");   // step-0 planes landed
    BARRIER;

    #pragma unroll
    for (int t = 0; t < 24; ++t) {
        const __bf16* buf = SL + (t % 3) * 16384;
        const __bf16* pA = buf + (wm * 128 + lr) * 32 + slotp * 8;
        const __bf16* pB = buf + 8192 + (wn * 64 + lr) * 32 + slotp * 8;
        bf16x8 af[4], bqf[4];
        // ---------- phase A ----------
        #pragma unroll
        for (int i = 0; i < 4; ++i) af[i] = *(const bf16x8*)(pA + i * 512);
        #pragma unroll
        for (int j = 0; j < 4; ++j) bqf[j] = *(const bf16x8*)(pB + j * 512);
        if (t + 2 < 24) stageA(t + 2);
        BARRIER;
        asm volatile("s_waitcnt lgkmcnt(0)" ::: "memory");
        __builtin_amdgcn_sched_barrier(0);
        __builtin_amdgcn_s_setprio(1);
        #pragma unroll
        for (int i = 0; i < 4; ++i)
            #pragma unroll
            for (int j = 0; j < 4; ++j)
                acc[i][j] = __builtin_amdgcn_mfma_f32_16x16x32_bf16(af[i], bqf[j], acc[i][j], 0, 0, 0);
        __builtin_amdgcn_s_setprio(0);
        BARRIER;
        // ---------- phase B ----------
        bf16x8 ag[4];
        #pragma unroll
        for (int i = 0; i < 4; ++i) ag[i] = *(const bf16x8*)(pA + (i + 4) * 512);
        if (t + 2 < 24) stageB(t + 2);
        if (t <= 21)      asm volatile("s_waitcnt vmcnt(4)" ::: "memory");
        else if (t == 22) asm volatile("s_waitcnt vmcnt(0)" ::: "memory");
        BARRIER;
        asm volatile("s_waitcnt lgkmcnt(0)" ::: "memory");
        __builtin_amdgcn_sched_barrier(0);
        __builtin_amdgcn_s_setprio(1);
        #pragma unroll
        for (int i = 0; i < 4; ++i)
            #pragma unroll
            for (int j = 0; j < 4; ++j)
                acc[i + 4][j] = __builtin_amdgcn_mfma_f32_16x16x32_bf16(ag[i], bqf[j], acc[i + 4][j], 0, 0, 0);
        __builtin_amdgcn_s_setprio(0);
        BARRIER;
    }

    const int row0 = kslc * 4;   // C/D: col=lane&15, row=(lane>>4)*4+reg
    if (MODE == 0) {
        __bf16* T = SL + wv * 2176;          // 16 x 136 per wave
        #pragma unroll
        for (int j = 0; j < 4; ++j) {
            __syncthreads();
            #pragma unroll
            for (int i = 0; i < 8; ++i) {
                bf16x4 v;
                #pragma unroll
                for (int r = 0; r < 4; ++r) {
                    const int mg = m0 + wm * 128 + i * 16 + row0 + r;
                    const float bb = (m0 < 768) ? bias_lo[mg] : bias_hi[mg - 768];
                    v[r] = (__bf16)(acc[i][j][r] + bb);
                }
                *(bf16x4*)(T + lr * 136 + i * 16 + row0) = v;
            }
            __syncthreads();
            const int rr = lane >> 2, seg = lane & 3;
            __bf16* dst = (__bf16*)Out + (size_t)(n0 + wn * 64 + j * 16 + rr) * ldo
                          + m0 + wm * 128 + seg * 32;
            const __bf16* src = T + rr * 136 + seg * 32;
            #pragma unroll
            for (int s = 0; s < 4; ++s)
                *(bf16x8*)(dst + s * 8) = *(const bf16x8*)(src + s * 8);
        }
    } else {
        const int b_ = n0 >> 11;
        const int l0 = (n0 & 2047) + wn * 64;
        float* o = (float*)Out;
        #pragma unroll
        for (int i = 0; i < 8; ++i)
            #pragma unroll
            for (int r = 0; r < 4; ++r) {
                const int mg = m0 + wm * 128 + i * 16 + row0 + r;
                const float bb = bias_lo[mg];
                #pragma unroll
                for (int j = 0; j < 4; ++j)
                    o[((size_t)(b_ * KD + mg)) * L_SEQ + l0 + j * 16 + lr] = acc[i][j][r] + bb;
            }
    }
}

// ---------------- attention (transposed, 16B loads) ----------------
// Qt: [8192][768]; KVt: [49152][1536] (K at +0, V at +768); attT: [8192][768]
__global__ __launch_bounds__(256) void attn_kernel(
    const __bf16* __restrict__ Qt, const __bf16* __restrict__ KVt,
    __bf16* __restrict__ attT)
{
    const int bid = blockIdx.x;
    const int lt = bid & 63;
    const int h = bid >> 6;
    const int tid = threadIdx.x;
    const int wave = tid >> 6, lane = tid & 63;
    const int half = lane >> 5, ln = lane & 31;
    const int n = lt * 128 + wave * 32 + ln;
    const int l = n & (L_SEQ - 1);
    const int c0 = h * 64 + half * 32;

    float q[32];
    {
        const __bf16* qp = Qt + (size_t)n * KD + c0;
        #pragma unroll
        for (int s = 0; s < 4; ++s) {
            const bf16x8 v = *(const bf16x8*)(qp + s * 8);
            #pragma unroll
            for (int j = 0; j < 8; ++j) q[s * 8 + j] = (float)v[j];
        }
    }

    float sc[10];
    #pragma unroll
    for (int w = 0; w < 5; ++w) {
        const int lw = l + w - 2;
        float acc = 0.f;
        if ((unsigned)lw < L_SEQ) {
            const __bf16* kp = KVt + (size_t)(n + w - 2) * KVLD + c0;
            #pragma unroll
            for (int s = 0; s < 4; ++s) {
                const bf16x8 v = *(const bf16x8*)(kp + s * 8);
                #pragma unroll
                for (int j = 0; j < 8; ++j) acc += q[s * 8 + j] * (float)v[j];
            }
        }
        sc[w] = acc;
    }
    #pragma unroll
    for (int a = 0; a < 5; ++a) {
        const __bf16* kp = KVt + ((size_t)(a + 1) * NX + n) * KVLD + c0;
        float acc = 0.f;
        #pragma unroll
        for (int s = 0; s < 4; ++s) {
            const bf16x8 v = *(const bf16x8*)(kp + s * 8);
            #pragma unroll
            for (int j = 0; j < 8; ++j) acc += q[s * 8 + j] * (float)v[j];
        }
        sc[5 + a] = acc;
    }

    #pragma unroll
    for (int i = 0; i < 10; ++i) {
        sc[i] += __shfl_xor(sc[i], 32);
        sc[i] *= 0.125f;
    }

    float mx = sc[0];
    #pragma unroll
    for (int i = 1; i < 10; ++i) mx = fmaxf(mx, sc[i]);
    float e[10], sum = 0.f;
    #pragma unroll
    for (int i = 0; i < 10; ++i) { e[i] = __expf(sc[i] - mx); sum += e[i]; }
    const float inv = 1.f / sum;

    float o[32];
    #pragma unroll
    for (int i = 0; i < 32; ++i) o[i] = 0.f;

    #pragma unroll
    for (int w = 0; w < 5; ++w) {
        const int lw = l + w - 2;
        if ((unsigned)lw < L_SEQ) {
            const __bf16* vp = KVt + (size_t)(n + w - 2) * KVLD + 768 + c0;
            #pragma unroll
            for (int s = 0; s < 4; ++s) {
                const bf16x8 v = *(const bf16x8*)(vp + s * 8);
                #pragma unroll
                for (int j = 0; j < 8; ++j) o[s * 8 + j] += e[w] * (float)v[j];
            }
        }
    }
    #pragma unroll
    for (int a = 0; a < 5; ++a) {
        const __bf16* vp = KVt + ((size_t)(a + 1) * NX + n) * KVLD + 768 + c0;
        #pragma unroll
        for (int s = 0; s < 4; ++s) {
            const bf16x8 v = *(const bf16x8*)(vp + s * 8);
            #pragma unroll
            for (int j = 0; j < 8; ++j) o[s * 8 + j] += e[5 + a] * (float)v[j];
        }
    }

    __bf16* dst = attT + (size_t)n * KD + c0;
    #pragma unroll
    for (int s = 0; s < 4; ++s) {
        bf16x8 t;
        #pragma unroll
        for (int j = 0; j < 8; ++j) t[j] = (__bf16)(o[s * 8 + j] * inv);
        *(bf16x8*)(dst + s * 8) = t;
    }
}

extern "C" void kernel_launch(void* const* d_in, const int* in_sizes, int n_in,
                              void* d_out, int out_size, void* d_ws, size_t ws_size,
                              hipStream_t stream)
{
    const float* x  = (const float*)d_in[0];
    const float* ax = (const float*)d_in[1];
    const float* Wq = (const float*)d_in[2];
    const float* bq = (const float*)d_in[3];
    const float* Wk = (const float*)d_in[4];
    const float* bk = (const float*)d_in[5];
    const float* Wv = (const float*)d_in[6];
    const float* bv = (const float*)d_in[7];
    const float* Wo = (const float*)d_in[8];
    const float* bo = (const float*)d_in[9];
    float* out = (float*)d_out;

    __bf16* p = (__bf16*)d_ws;
    __bf16* Wq_bf = p; p += 589824;
    __bf16* Wkv_bf = p;                       // [Wk_bf; Wv_bf] contiguous
    __bf16* Wk_bf = p; p += 589824;
    __bf16* Wv_bf = p; p += 589824;
    __bf16* Wo_bf = p; p += 589824;
    __bf16* Qt    = p; p += (size_t)KD * NX;
    __bf16* KVt   = p; p += (size_t)KVLD * NALL;
    __bf16* XT    = p; p += (size_t)KD * NALL;
    __bf16* attT  = p;

    const size_t lds = 98304;   // 3 x 32 KiB ring

    wconv_kernel<<<dim3(576, 4), dim3(256), 0, stream>>>(Wq, Wk, Wv, Wo, Wq_bf, Wk_bf, Wv_bf, Wo_bf);
    xconv_kernel<<<dim3(768, 12), dim3(256), 0, stream>>>(x, ax, XT);

    gemm256_kernel<0, 6><<<dim3(1152), dim3(512), lds, stream>>>(Wkv_bf, XT, bk, bv, KVt, KVLD);
    gemm256_kernel<0, 3><<<dim3(96),  dim3(512), lds, stream>>>(Wq_bf, XT, bq, bq, Qt, KD);

    attn_kernel<<<dim3(64 * N_HEAD), dim3(256), 0, stream>>>(Qt, KVt, attT);

    gemm256_kernel<1, 3><<<dim3(96),  dim3(512), lds, stream>>>(Wo_bf, attT, bo, bo, out, 0);
}

// Round 7
// 306.065 us; speedup vs baseline: 1.0132x; 1.0086x over previous
//
#include <hip/hip_runtime.h>
#include <hip/hip_bf16.h>
#include <cstddef>
#include <cstdint>

typedef __attribute__((ext_vector_type(4))) __bf16 bf16x4;
typedef __attribute__((ext_vector_type(8))) __bf16 bf16x8;
typedef __attribute__((ext_vector_type(4))) float f32x4;

#define L_SEQ 2048
#define KD 768
#define N_HEAD 12
#define NB 4
#define NX 8192          // B*L
#define NALL 49152       // B*L*(1+5)
#define KVLD 1536        // merged K|V output row length

#define FENCE asm volatile("" ::: "memory")
#define BARRIER do { FENCE; __builtin_amdgcn_s_barrier(); FENCE; } while (0)

__device__ __forceinline__ void gload16(const __bf16* g, __bf16* l) {
    __builtin_amdgcn_global_load_lds(
        (const __attribute__((address_space(1))) void*)g,
        (__attribute__((address_space(3))) void*)l, 16, 0, 0);
}

// ---------------- weight fp32 -> bf16 ----------------
__global__ __launch_bounds__(256) void wconv_kernel(
    const float* __restrict__ W0, const float* __restrict__ W1,
    const float* __restrict__ W2, const float* __restrict__ W3,
    __bf16* __restrict__ O0, __bf16* __restrict__ O1,
    __bf16* __restrict__ O2, __bf16* __restrict__ O3)
{
    const float* src; __bf16* dst;
    switch (blockIdx.y) {
        case 0: src = W0; dst = O0; break;
        case 1: src = W1; dst = O1; break;
        case 2: src = W2; dst = O2; break;
        default: src = W3; dst = O3; break;
    }
    const int i = (blockIdx.x * 256 + threadIdx.x) * 4;
    const float4 v = *(const float4*)(src + i);
    bf16x4 t;
    t[0] = (__bf16)v.x; t[1] = (__bf16)v.y; t[2] = (__bf16)v.z; t[3] = (__bf16)v.w;
    *(bf16x4*)(dst + i) = t;
}

// ------------- convert+transpose into XT[n'(49152)][768] -------------
__global__ __launch_bounds__(256) void xconv_kernel(
    const float* __restrict__ x, const float* __restrict__ ax,
    __bf16* __restrict__ XT)
{
    __shared__ __bf16 S[64][72];
    const int t = threadIdx.x;
    const int ap = blockIdx.x >> 7;
    const int inner = blockIdx.x & 127;
    const int bb = inner >> 5;
    const int l0 = (inner & 31) * 64;
    const int d0 = blockIdx.y * 64;
    const int r = t >> 4;
    const int c4 = (t & 15) * 4;
    #pragma unroll
    for (int p = 0; p < 4; ++p) {
        const int d = d0 + r + p * 16;
        const float* src = (ap == 0)
            ? x + ((size_t)(bb * KD + d)) * L_SEQ
            : ax + (((size_t)(bb * KD + d)) * 5 + (ap - 1)) * L_SEQ;
        const float4 v = *(const float4*)(src + l0 + c4);
        S[c4 + 0][r + p * 16] = (__bf16)v.x;
        S[c4 + 1][r + p * 16] = (__bf16)v.y;
        S[c4 + 2][r + p * 16] = (__bf16)v.z;
        S[c4 + 3][r + p * 16] = (__bf16)v.w;
    }
    __syncthreads();
    #pragma unroll
    for (int p = 0; p < 4; ++p) {
        const int lr = r + p * 16;
        const bf16x4 v = *(const bf16x4*)&S[lr][c4];
        *(bf16x4*)(XT + ((size_t)ap * NX + bb * L_SEQ + l0 + lr) * KD + d0 + c4) = v;
    }
}

// ---------------- 256x256 read-ahead pipelined GEMM (BK=32, 2 phases/step) ----------------
// Out = A[M][768] * Bt[N][768]^T + bias. 8 waves (2M x 4N), per-wave 128x64 (acc[8][4]).
// LDS: 3-deep ring of (A 16KB + B 16KB) = 96 KiB.
// Step t: { read R2(t)=af[4..7] ; stageA(t+2) ; lgkm(4)->drain R1(t) ; MFMA-A ;
//           stageB(t+2) ; vmcnt(4) ; BARRIER(publish t+1) ;
//           read R1(t+1)=af[0..3]+bq(t+1) ; lgkm(8)->drain R2(t) ; MFMA-B ; BARRIER(WAR) }
// ds_reads issue >=1 MFMA-cluster before their drain -> LDS latency hidden.
// B-frags ping-pong (bqf[8]); all buffer roles distinct mod 3.
template <int MODE, int NM>   // MODE 0: bf16 OutT[n'][ldo]; MODE 1: fp32 out[(b*768+m)*2048+l]
__global__ __launch_bounds__(512, 1) void gemm256_kernel(
    const __bf16* __restrict__ A, const __bf16* __restrict__ Bt,
    const float* __restrict__ bias_lo, const float* __restrict__ bias_hi,
    void* __restrict__ Out, int ldo)
{
    extern __shared__ __bf16 SL[];
    // XCD-grouped swizzle: same-n-panel m-blocks land consecutively on one XCD
    const int nwg8 = gridDim.x >> 3;
    const int gidx = (blockIdx.x & 7) * nwg8 + (blockIdx.x >> 3);
    const int m0 = (gidx % NM) * 256;
    const int n0 = (gidx / NM) * 256;

    const int tid = threadIdx.x;
    const int lane = tid & 63, wv = tid >> 6;
    const int wm = wv >> 2, wn = wv & 3;
    const int lr = lane & 15;
    const int kslc = lane >> 4;
    const int slotp = kslc ^ ((lr >> 1) & 3);
    const int srow = lane >> 2;
    const int skoff = ((lane & 3) ^ ((lane >> 3) & 3)) * 8;

    f32x4 acc[8][4];
    #pragma unroll
    for (int i = 0; i < 8; ++i)
        #pragma unroll
        for (int j = 0; j < 4; ++j)
            acc[i][j] = (f32x4){0.f, 0.f, 0.f, 0.f};

    const size_t gbA = (size_t)m0 * KD + skoff;
    const size_t gbB = (size_t)n0 * KD + skoff;

    auto stageA = [&](int t) {
        __bf16* dst = SL + (t % 3) * 16384;
        #pragma unroll
        for (int i2 = 0; i2 < 2; ++i2) {
            const int c = wv + i2 * 8;
            gload16(A + gbA + (size_t)(c * 16 + srow) * KD + t * 32, dst + c * 512);
        }
    };
    auto stageB = [&](int t) {
        __bf16* dst = SL + (t % 3) * 16384 + 8192;
        #pragma unroll
        for (int i2 = 0; i2 < 2; ++i2) {
            const int c = wv + i2 * 8;
            gload16(Bt + gbB + (size_t)(c * 16 + srow) * KD + t * 32, dst + c * 512);
        }
    };

    const int offA = (wm * 128 + lr) * 32 + slotp * 8;
    const int offB = 8192 + (wn * 64 + lr) * 32 + slotp * 8;

    // prologue: steps 0,1 in flight; wait step 0; pre-read R1(0)
    stageA(0); stageB(0); stageA(1); stageB(1);
    asm volatile("s_waitcnt vmcnt(4)" ::: "memory");
    BARRIER;

    bf16x8 af[8], bqf[8];
    #pragma unroll
    for (int i = 0; i < 4; ++i) af[i] = *(const bf16x8*)(SL + offA + i * 512);
    #pragma unroll
    for (int j = 0; j < 4; ++j) bqf[j] = *(const bf16x8*)(SL + offB + j * 512);

    #pragma unroll
    for (int t = 0; t < 24; ++t) {
        const int cur = (t & 1) * 4, nxt = 4 - cur;
        const __bf16* buf  = SL + (t % 3) * 16384;
        const __bf16* bufn = SL + ((t + 1) % 3) * 16384;

        // ---- phase A ----
        #pragma unroll
        for (int i = 0; i < 4; ++i) af[4 + i] = *(const bf16x8*)(buf + offA + (i + 4) * 512);  // R2(t)
        if (t + 2 < 24) stageA(t + 2);
        asm volatile("s_waitcnt lgkmcnt(4)" ::: "memory");   // drain R1(t); keep R2(t) in flight
        __builtin_amdgcn_sched_barrier(0);
        __builtin_amdgcn_s_setprio(1);
        #pragma unroll
        for (int i = 0; i < 4; ++i)
            #pragma unroll
            for (int j = 0; j < 4; ++j)
                acc[i][j] = __builtin_amdgcn_mfma_f32_16x16x32_bf16(af[i], bqf[cur + j], acc[i][j], 0, 0, 0);
        __builtin_amdgcn_s_setprio(0);

        // ---- phase B ----
        if (t + 2 < 24) stageB(t + 2);
        if (t <= 21)      asm volatile("s_waitcnt vmcnt(4)" ::: "memory");
        else if (t == 22) asm volatile("s_waitcnt vmcnt(0)" ::: "memory");
        BARRIER;                                              // publish buf t+1
        if (t < 23) {
            #pragma unroll
            for (int i = 0; i < 4; ++i) af[i] = *(const bf16x8*)(bufn + offA + i * 512);       // R1(t+1)
            #pragma unroll
            for (int j = 0; j < 4; ++j) bqf[nxt + j] = *(const bf16x8*)(bufn + offB + j * 512);
            asm volatile("s_waitcnt lgkmcnt(8)" ::: "memory");  // drain R2(t); keep R1(t+1)
        } else {
            asm volatile("s_waitcnt lgkmcnt(0)" ::: "memory");
        }
        __builtin_amdgcn_sched_barrier(0);
        __builtin_amdgcn_s_setprio(1);
        #pragma unroll
        for (int i = 0; i < 4; ++i)
            #pragma unroll
            for (int j = 0; j < 4; ++j)
                acc[i + 4][j] = __builtin_amdgcn_mfma_f32_16x16x32_bf16(af[4 + i], bqf[cur + j], acc[i + 4][j], 0, 0, 0);
        __builtin_amdgcn_s_setprio(0);
        BARRIER;                                              // WAR: buf t free for stage(t+3)
    }

    const int row0 = kslc * 4;   // C/D: col=lane&15, row=(lane>>4)*4+reg
    if (MODE == 0) {
        __bf16* T = SL + wv * 2176;          // 16 x 136 per wave
        #pragma unroll
        for (int j = 0; j < 4; ++j) {
            __syncthreads();
            #pragma unroll
            for (int i = 0; i < 8; ++i) {
                bf16x4 v;
                #pragma unroll
                for (int r = 0; r < 4; ++r) {
                    const int mg = m0 + wm * 128 + i * 16 + row0 + r;
                    const float bb = (m0 < 768) ? bias_lo[mg] : bias_hi[mg - 768];
                    v[r] = (__bf16)(acc[i][j][r] + bb);
                }
                *(bf16x4*)(T + lr * 136 + i * 16 + row0) = v;
            }
            __syncthreads();
            const int rr = lane >> 2, seg = lane & 3;
            __bf16* dst = (__bf16*)Out + (size_t)(n0 + wn * 64 + j * 16 + rr) * ldo
                          + m0 + wm * 128 + seg * 32;
            const __bf16* src = T + rr * 136 + seg * 32;
            #pragma unroll
            for (int s = 0; s < 4; ++s)
                *(bf16x8*)(dst + s * 8) = *(const bf16x8*)(src + s * 8);
        }
    } else {
        const int b_ = n0 >> 11;
        const int l0 = (n0 & 2047) + wn * 64;
        float* o = (float*)Out;
        #pragma unroll
        for (int i = 0; i < 8; ++i)
            #pragma unroll
            for (int r = 0; r < 4; ++r) {
                const int mg = m0 + wm * 128 + i * 16 + row0 + r;
                const float bb = bias_lo[mg];
                #pragma unroll
                for (int j = 0; j < 4; ++j)
                    o[((size_t)(b_ * KD + mg)) * L_SEQ + l0 + j * 16 + lr] = acc[i][j][r] + bb;
            }
    }
}

// ---------------- attention (transposed, 16B loads) ----------------
// Qt: [8192][768]; KVt: [49152][1536] (K at +0, V at +768); attT: [8192][768]
__global__ __launch_bounds__(256) void attn_kernel(
    const __bf16* __restrict__ Qt, const __bf16* __restrict__ KVt,
    __bf16* __restrict__ attT)
{
    const int bid = blockIdx.x;
    const int lt = bid & 63;
    const int h = bid >> 6;
    const int tid = threadIdx.x;
    const int wave = tid >> 6, lane = tid & 63;
    const int half = lane >> 5, ln = lane & 31;
    const int n = lt * 128 + wave * 32 + ln;
    const int l = n & (L_SEQ - 1);
    const int c0 = h * 64 + half * 32;

    float q[32];
    {
        const __bf16* qp = Qt + (size_t)n * KD + c0;
        #pragma unroll
        for (int s = 0; s < 4; ++s) {
            const bf16x8 v = *(const bf16x8*)(qp + s * 8);
            #pragma unroll
            for (int j = 0; j < 8; ++j) q[s * 8 + j] = (float)v[j];
        }
    }

    float sc[10];
    #pragma unroll
    for (int w = 0; w < 5; ++w) {
        const int lw = l + w - 2;
        float acc = 0.f;
        if ((unsigned)lw < L_SEQ) {
            const __bf16* kp = KVt + (size_t)(n + w - 2) * KVLD + c0;
            #pragma unroll
            for (int s = 0; s < 4; ++s) {
                const bf16x8 v = *(const bf16x8*)(kp + s * 8);
                #pragma unroll
                for (int j = 0; j < 8; ++j) acc += q[s * 8 + j] * (float)v[j];
            }
        }
        sc[w] = acc;
    }
    #pragma unroll
    for (int a = 0; a < 5; ++a) {
        const __bf16* kp = KVt + ((size_t)(a + 1) * NX + n) * KVLD + c0;
        float acc = 0.f;
        #pragma unroll
        for (int s = 0; s < 4; ++s) {
            const bf16x8 v = *(const bf16x8*)(kp + s * 8);
            #pragma unroll
            for (int j = 0; j < 8; ++j) acc += q[s * 8 + j] * (float)v[j];
        }
        sc[5 + a] = acc;
    }

    #pragma unroll
    for (int i = 0; i < 10; ++i) {
        sc[i] += __shfl_xor(sc[i], 32);
        sc[i] *= 0.125f;
    }

    float mx = sc[0];
    #pragma unroll
    for (int i = 1; i < 10; ++i) mx = fmaxf(mx, sc[i]);
    float e[10], sum = 0.f;
    #pragma unroll
    for (int i = 0; i < 10; ++i) { e[i] = __expf(sc[i] - mx); sum += e[i]; }
    const float inv = 1.f / sum;

    float o[32];
    #pragma unroll
    for (int i = 0; i < 32; ++i) o[i] = 0.f;

    #pragma unroll
    for (int w = 0; w < 5; ++w) {
        const int lw = l + w - 2;
        if ((unsigned)lw < L_SEQ) {
            const __bf16* vp = KVt + (size_t)(n + w - 2) * KVLD + 768 + c0;
            #pragma unroll
            for (int s = 0; s < 4; ++s) {
                const bf16x8 v = *(const bf16x8*)(vp + s * 8);
                #pragma unroll
                for (int j = 0; j < 8; ++j) o[s * 8 + j] += e[w] * (float)v[j];
            }
        }
    }
    #pragma unroll
    for (int a = 0; a < 5; ++a) {
        const __bf16* vp = KVt + ((size_t)(a + 1) * NX + n) * KVLD + 768 + c0;
        #pragma unroll
        for (int s = 0; s < 4; ++s) {
            const bf16x8 v = *(const bf16x8*)(vp + s * 8);
            #pragma unroll
            for (int j = 0; j < 8; ++j) o[s * 8 + j] += e[5 + a] * (float)v[j];
        }
    }

    __bf16* dst = attT + (size_t)n * KD + c0;
    #pragma unroll
    for (int s = 0; s < 4; ++s) {
        bf16x8 t;
        #pragma unroll
        for (int j = 0; j < 8; ++j) t[j] = (__bf16)(o[s * 8 + j] * inv);
        *(bf16x8*)(dst + s * 8) = t;
    }
}

extern "C" void kernel_launch(void* const* d_in, const int* in_sizes, int n_in,
                              void* d_out, int out_size, void* d_ws, size_t ws_size,
                              hipStream_t stream)
{
    const float* x  = (const float*)d_in[0];
    const float* ax = (const float*)d_in[1];
    const float* Wq = (const float*)d_in[2];
    const float* bq = (const float*)d_in[3];
    const float* Wk = (const float*)d_in[4];
    const float* bk = (const float*)d_in[5];
    const float* Wv = (const float*)d_in[6];
    const float* bv = (const float*)d_in[7];
    const float* Wo = (const float*)d_in[8];
    const float* bo = (const float*)d_in[9];
    float* out = (float*)d_out;

    __bf16* p = (__bf16*)d_ws;
    __bf16* Wq_bf = p; p += 589824;
    __bf16* Wkv_bf = p;                       // [Wk_bf; Wv_bf] contiguous
    __bf16* Wk_bf = p; p += 589824;
    __bf16* Wv_bf = p; p += 589824;
    __bf16* Wo_bf = p; p += 589824;
    __bf16* Qt    = p; p += (size_t)KD * NX;
    __bf16* KVt   = p; p += (size_t)KVLD * NALL;
    __bf16* XT    = p; p += (size_t)KD * NALL;
    __bf16* attT  = p;

    const size_t lds = 98304;   // 3 x 32 KiB ring

    wconv_kernel<<<dim3(576, 4), dim3(256), 0, stream>>>(Wq, Wk, Wv, Wo, Wq_bf, Wk_bf, Wv_bf, Wo_bf);
    xconv_kernel<<<dim3(768, 12), dim3(256), 0, stream>>>(x, ax, XT);

    gemm256_kernel<0, 6><<<dim3(1152), dim3(512), lds, stream>>>(Wkv_bf, XT, bk, bv, KVt, KVLD);
    gemm256_kernel<0, 3><<<dim3(96),  dim3(512), lds, stream>>>(Wq_bf, XT, bq, bq, Qt, KD);

    attn_kernel<<<dim3(64 * N_HEAD), dim3(256), 0, stream>>>(Qt, KVt, attT);

    gemm256_kernel<1, 3><<<dim3(96),  dim3(512), lds, stream>>>(Wo_bf, attT, bo, bo, out, 0);
}